// Round 14
// baseline (274.069 us; speedup 1.0000x reference)
//
#include <hip/hip_runtime.h>
#include <hip/hip_bf16.h>
#include <cstdint>
#include <cstddef>

typedef __bf16 bf16;
typedef __attribute__((ext_vector_type(2))) __bf16 bf16x2;
typedef __attribute__((ext_vector_type(4))) __bf16 bf16x4;
typedef __attribute__((ext_vector_type(8))) __bf16 bf16x8;
typedef __attribute__((ext_vector_type(4))) float f32x4;

#define MFMA16(a, b, c) __builtin_amdgcn_mfma_f32_16x16x32_bf16((a), (b), (c), 0, 0, 0)
// softmax runs in exp2 domain; scale folded into QCR GEMM epilogue
#define SCALE_L2E 0.127517432f

//  QCR row: [0..2047]=q_c (h*128+d), [2048..3071]=q_r (h*64+r)    stride 3072
//  KVKR row: [0..2047]=k_c, [2048..4095]=v, [4096..4159]=k_r      stride 4160
#define QCR_STRIDE 3072
#define KV_STRIDE  4160

__device__ __forceinline__ void gload16(const void* g, void* l) {
    __builtin_amdgcn_global_load_lds(
        (const __attribute__((address_space(1))) void*)g,
        (__attribute__((address_space(3))) void*)l, 16, 0, 0);
}

// barrier WITHOUT vmcnt drain (register prefetch stays in flight)
__device__ __forceinline__ void bar_lgkm() {
    asm volatile("s_waitcnt lgkmcnt(0)" ::: "memory");
    __builtin_amdgcn_s_barrier();
    asm volatile("" ::: "memory");
}

__device__ __forceinline__ int pack_bf16(float a, float b) {
    bf16x2 p; p[0] = (bf16)a; p[1] = (bf16)b;
    return __builtin_bit_cast(int, p);
}

// ---------------- merged convert dispatch ----------------
__global__ __launch_bounds__(256) void k_cvtAll(
    const float* __restrict__ w_ckv, const float* __restrict__ w_kv,
    const float* __restrict__ w_cq, const float* __restrict__ w_q,
    const float* __restrict__ w_qr, const float* __restrict__ w_kr,
    bf16* __restrict__ WCT, bf16* __restrict__ WKVKRT, bf16* __restrict__ WQQRT,
    const float* __restrict__ x, bf16* __restrict__ XB)
{
    __shared__ float tile[32][33];
    int bid = blockIdx.x;
    const int t = threadIdx.x;
    if (bid >= 5664) {
        int n4 = (4096 * 2048) / 4;
        int i = (bid - 5664) * 256 + t;
        int stride = 2048 * 256;
        const float4* in4 = (const float4*)x;
        bf16x4* o4 = (bf16x4*)XB;
        for (; i < n4; i += stride) {
            float4 v = in4[i];
            bf16x4 o;
            o[0] = (bf16)v.x; o[1] = (bf16)v.y; o[2] = (bf16)v.z; o[3] = (bf16)v.w;
            o4[i] = o;
        }
        return;
    }
    const float* src; bf16* dst; int Kd, Nd, loc;
    if (bid < 1024)      { src = w_ckv; dst = WCT;                   Kd = 2048; Nd = 512;  loc = bid; }
    else if (bid < 3072) { src = w_kv;  dst = WKVKRT;                Kd = 512;  Nd = 4096; loc = bid - 1024; }
    else if (bid < 4096) { src = w_cq;  dst = WCT + 512ull * 2048;   Kd = 2048; Nd = 512;  loc = bid - 3072; }
    else if (bid < 5120) { src = w_q;   dst = WQQRT;                 Kd = 512;  Nd = 2048; loc = bid - 4096; }
    else if (bid < 5632) { src = w_qr;  dst = WQQRT + 2048ull * 512; Kd = 512;  Nd = 1024; loc = bid - 5120; }
    else                 { src = w_kr;  dst = WKVKRT + 4096ull * 512; Kd = 512; Nd = 64;   loc = bid - 5632; }
    const int nbx = Nd / 32;
    const int n0 = (loc % nbx) * 32, k0 = (loc / nbx) * 32;
    const int r = t >> 3, c4 = (t & 7) * 4;
    float4 v = *(const float4*)(src + (size_t)(k0 + r) * Nd + n0 + c4);
    tile[r][c4 + 0] = v.x; tile[r][c4 + 1] = v.y;
    tile[r][c4 + 2] = v.z; tile[r][c4 + 3] = v.w;
    __syncthreads();
    bf16x4 o;
    o[0] = (bf16)tile[c4 + 0][r]; o[1] = (bf16)tile[c4 + 1][r];
    o[2] = (bf16)tile[c4 + 2][r]; o[3] = (bf16)tile[c4 + 3][r];
    *(bf16x4*)(dst + (size_t)(n0 + r) * Kd + k0 + c4) = o;
}

// ---------------- f32 -> bf16 transpose-convert (single weight, w_out) ----------------
__global__ __launch_bounds__(256) void k_cvtT(const float* __restrict__ in,
                                              bf16* __restrict__ out, int Kd, int Nd)
{
    __shared__ float tile[32][33];
    const int k0 = blockIdx.y * 32, n0 = blockIdx.x * 32;
    const int t = threadIdx.x;
    const int r = t >> 3, c4 = (t & 7) * 4;
    float4 v = *(const float4*)(in + (size_t)(k0 + r) * Nd + n0 + c4);
    tile[r][c4 + 0] = v.x; tile[r][c4 + 1] = v.y;
    tile[r][c4 + 2] = v.z; tile[r][c4 + 3] = v.w;
    __syncthreads();
    bf16x4 o;
    o[0] = (bf16)tile[c4 + 0][r]; o[1] = (bf16)tile[c4 + 1][r];
    o[2] = (bf16)tile[c4 + 2][r]; o[3] = (bf16)tile[c4 + 3][r];
    *(bf16x4*)(out + (size_t)(n0 + r) * Kd + k0 + c4) = o;
}

// ---------------- shared GEMM body ----------------
template<int MF, int NF, bool F32OUT, bool ROPE>
__device__ __forceinline__ void gemm_body(
    const bf16* __restrict__ A, const bf16* __restrict__ BT,
    bf16* __restrict__ Cb, float* __restrict__ Cf,
    int M, int N, int K, int lda, float cscale, int ropeStart, int bx, int by,
    bf16* As, bf16* Bs)
{
    constexpr int ASTR = MF * 1024, BSTR = NF * 1024;
    const int t = threadIdx.x;
    const int m0 = by * (MF * 32);
    const int n0 = bx * (NF * 32);
    const int wid = t >> 6, lane = t & 63;
    const int wm = (wid >> 1) * (MF * 16), wn = (wid & 1) * (NF * 16);
    const int lr = lane & 15, lk = (lane >> 4) * 8;

    const int srow = t >> 2, skc = (t & 3) << 3;
    const int bn0 = min(n0 + srow, N - 1);
    const int bn1 = min(n0 + srow + 64, N - 1);

    f32x4 acc[MF][NF];
    const f32x4 z = {0.f, 0.f, 0.f, 0.f};
#pragma unroll
    for (int m = 0; m < MF; ++m)
#pragma unroll
        for (int n = 0; n < NF; ++n) acc[m][n] = z;

    auto stage = [&](int buf, int k0) {
        gload16(BT + (size_t)bn0 * K + k0 + skc, Bs + buf * BSTR + t * 8);
        if constexpr (NF == 4)
            gload16(BT + (size_t)bn1 * K + k0 + skc, Bs + buf * BSTR + (t + 256) * 8);
        gload16(A + (size_t)(m0 + srow) * lda + k0 + skc, As + buf * ASTR + t * 8);
        if constexpr (MF == 4)
            gload16(A + (size_t)(m0 + srow + 64) * lda + k0 + skc, As + buf * ASTR + (t + 256) * 8);
    };

    stage(0, 0);
    __syncthreads();

    for (int k0 = 0; k0 < K; k0 += 32) {
        const int cur = (k0 >> 5) & 1;
        if (k0 + 32 < K) stage(cur ^ 1, k0 + 32);

        bf16x8 af[MF], bfr[NF];
#pragma unroll
        for (int m = 0; m < MF; ++m)
            af[m] = *(const bf16x8*)(As + cur * ASTR + (wm + m * 16 + lr) * 32 + lk);
#pragma unroll
        for (int n = 0; n < NF; ++n)
            bfr[n] = *(const bf16x8*)(Bs + cur * BSTR + (wn + n * 16 + lr) * 32 + lk);
#pragma unroll
        for (int m = 0; m < MF; ++m)
#pragma unroll
            for (int n = 0; n < NF; ++n)
                acc[m][n] = MFMA16(af[m], bfr[n], acc[m][n]);

        __syncthreads();
    }

    const int lrow4 = (lane >> 4) * 4;
#pragma unroll
    for (int m = 0; m < MF; ++m)
#pragma unroll
        for (int n = 0; n < NF; ++n)
#pragma unroll
            for (int i = 0; i < 4; ++i) {
                int r = m0 + wm + m * 16 + lrow4 + i;
                int c = n0 + wn + n * 16 + lr;
                float val = acc[m][n][i] * cscale;
                if constexpr (ROPE) {
                    float part = __shfl_xor(val, 1, 64);
                    if (c >= ropeStart) {
                        int i2 = ((c - ropeStart) & 63) >> 1;
                        int s = r & 2047;
                        float ang = (float)s * __expf(-(float)i2 * 0.28782313662f);
                        float sn, cs;
                        __sincosf(ang, &sn, &cs);
                        val = (c & 1) ? (part * sn + val * cs)
                                      : (val * cs - part * sn);
                    }
                }
                if (r < M && c < N) {
                    if constexpr (F32OUT) Cf[(size_t)r * N + c] = val;
                    else Cb[(size_t)r * N + c] = (bf16)val;
                }
            }
}

template<int MF, int NF, bool F32OUT>
__global__ __launch_bounds__(256) void k_gemm_bt(
    const bf16* __restrict__ A, const bf16* __restrict__ BT,
    bf16* __restrict__ Cb, float* __restrict__ Cf,
    int M, int N, int K, int lda, float cscale)
{
    __shared__ bf16 As[2 * MF * 1024];
    __shared__ bf16 Bs[2 * NF * 1024];
    gemm_body<MF, NF, F32OUT, false>(A, BT, Cb, Cf, M, N, K, lda, cscale, 1 << 30,
                                     blockIdx.x, blockIdx.y, As, Bs);
}

// KVKR (1056 blocks) + QCR (768 blocks) fused, RoPE in epilogue.
__global__ __launch_bounds__(256) void k_gemm_dual(
    const bf16* __restrict__ C, const bf16* __restrict__ WKVKRT,
    const bf16* __restrict__ WQQRT, bf16* __restrict__ KVKR, bf16* __restrict__ QCR)
{
    __shared__ bf16 As[2 * 4096];
    __shared__ bf16 Bs[2 * 4096];
    int bid = blockIdx.x;
    if (bid < 1056) {
        gemm_body<4, 4, false, true>(C, WKVKRT, KVKR, nullptr, 4096, 4160, 512, 1024,
                                     1.0f, 4096, bid % 33, bid / 33, As, Bs);
    } else {
        bid -= 1056;
        gemm_body<4, 4, false, true>(C + 512, WQQRT, QCR, nullptr, 4096, 3072, 512, 1024,
                                     SCALE_L2E, 2048, bid % 24, bid / 24, As, Bs);
    }
}

// ---------------- causal MLA attention (swapped QK^T, in-register P, 2 Q-frags) ----------------
// 512 blocks x 256 threads; block = one 128-row q-tile (4 waves x 32 rows).
// Complementary-qt pairing: under round-robin-XCD / sequential-CU dispatch,
// blocks L and L+256 co-reside on one CU; qt = (L<256) ? 15-(L>>5) : (L>>5)-8
// gives the pair (15-p, p) -> 34 staged tiles per CU pair, uniform.
// launch_bounds WITHOUT min-waves: r13's (256,2) capped VGPR at 128 -> spills.
__global__ __launch_bounds__(256) void k_attn(
    const bf16* __restrict__ qcr, const bf16* __restrict__ kvkr,
    bf16* __restrict__ att)
{
    __shared__ bf16 Ksc[64 * 128];  // [rho(key)][feat 0..127], 16B-block swizzled
    __shared__ bf16 Ksr[64 * 64];   // [rho(key)][feat 128..191], swizzled
    __shared__ bf16 Vt[128 * 64];   // [feat][key], 16B-block swizzled

    const int L = blockIdx.x;
    const int p = L >> 5;
    const int qt = (L < 256) ? (15 - p) : (p - 8);   // complementary pairing
    const int bh = L & 31;
    const int h = bh & 15, b = bh >> 4;

    const int t = threadIdx.x;
    const int wid = t >> 6, lane = t & 63;
    const int lr = lane & 15, lq = lane >> 4, lk = lq * 8;
    const size_t rowbase = (size_t)b * 2048;

    const f32x4 z = {0.f, 0.f, 0.f, 0.f};

    auto rho = [](int r) {
        return (((r >> 5) & 1) << 5) | (((r >> 2) & 1) << 4) | (((r >> 3) & 3) << 2) | (r & 3);
    };

    const int vk = (t & 31) * 2;
    const int vf = (t >> 5) * 8;

    bf16x8 rc[4], rr[2], rv[4];
    auto LOAD = [&](int kb) {
#pragma unroll
        for (int i = 0; i < 4; ++i) {
            int bb = t + 256 * i;
            int row = bb >> 4, gcb = bb & 15;
            rc[i] = *(const bf16x8*)(kvkr + (rowbase + kb + row) * KV_STRIDE + h * 128 + gcb * 8);
        }
#pragma unroll
        for (int i = 0; i < 2; ++i) {
            int bb = t + 256 * i;
            int row = bb >> 3, gcb = bb & 7;
            rr[i] = *(const bf16x8*)(kvkr + (rowbase + kb + row) * KV_STRIDE + 4096 + gcb * 8);
        }
#pragma unroll
        for (int i = 0; i < 2; ++i) {
            const bf16* vs = kvkr + (rowbase + kb + vk) * KV_STRIDE + 2048 + h * 128 + vf + 64 * i;
            rv[2 * i]     = *(const bf16x8*)vs;
            rv[2 * i + 1] = *(const bf16x8*)(vs + KV_STRIDE);
        }
    };
    auto WRITE = [&]() {
#pragma unroll
        for (int i = 0; i < 4; ++i) {
            int bb = t + 256 * i;
            int row = rho(bb >> 4), gcb = bb & 15;
            int scb = (gcb & 8) | ((gcb ^ row) & 7);
            *(bf16x8*)(Ksc + row * 128 + scb * 8) = rc[i];
        }
#pragma unroll
        for (int i = 0; i < 2; ++i) {
            int bb = t + 256 * i;
            int row = rho(bb >> 3), gcb = bb & 7;
            int scb = (gcb ^ row) & 7;
            *(bf16x8*)(Ksr + row * 64 + scb * 8) = rr[i];
        }
#pragma unroll
        for (int i = 0; i < 2; ++i)
#pragma unroll
            for (int j = 0; j < 8; ++j) {
                int feat = vf + 64 * i + j;
                int scb = ((vk >> 3) ^ (feat & 7)) & 7;
                bf16x2 pr; pr[0] = rv[2 * i][j]; pr[1] = rv[2 * i + 1][j];
                *(bf16x2*)(Vt + feat * 64 + scb * 8 + (vk & 7)) = pr;
            }
    };

    const int qrow_w = qt * 128 + wid * 32;      // wave's first row (32 rows/wave)
    const int qi0 = qrow_w + lr;                 // frag-0 row
    const int qi1 = qrow_w + 16 + lr;            // frag-1 row

    // Q fragments (pre-scaled by SCALE_L2E in the QCR GEMM)
    bf16x8 qf[2][6];
#pragma unroll
    for (int f = 0; f < 2; ++f) {
        const size_t qrow = rowbase + qrow_w + f * 16 + lr;
        const bf16* qp = qcr + qrow * QCR_STRIDE + h * 128;
#pragma unroll
        for (int ks = 0; ks < 4; ++ks) qf[f][ks] = *(const bf16x8*)(qp + ks * 32 + lk);
        const bf16* qp2 = qcr + qrow * QCR_STRIDE + 2048 + h * 64;
#pragma unroll
        for (int ks = 0; ks < 2; ++ks) qf[f][4 + ks] = *(const bf16x8*)(qp2 + ks * 32 + lk);
    }

    float mrow0 = -3e38f, lsum0 = 0.f;
    float mrow1 = -3e38f, lsum1 = 0.f;
    f32x4 o[2][8];
#pragma unroll
    for (int f = 0; f < 2; ++f)
#pragma unroll
        for (int n = 0; n < 8; ++n) o[f][n] = z;

    const int nkt = 2 * qt + 2;
    LOAD(0);

#pragma unroll 1
    for (int kt = 0; kt < nkt; ++kt) {
        const int kb = kt * 64;
        bar_lgkm();
        WRITE();
        if (kt + 1 < nkt) LOAD(kb + 64);
        bar_lgkm();

        if (kb > qrow_w + 31) continue;   // tile fully above this wave's 32 rows

        // ---- S^T = K Q^T (each kf read feeds BOTH Q fragments) ----
        f32x4 sacc0[4], sacc1[4];
        __builtin_amdgcn_s_setprio(1);
#pragma unroll
        for (int kg = 0; kg < 4; ++kg) {
            f32x4 s0 = z, s1 = z;
            const int key = kg * 16 + lr;
#pragma unroll
            for (int ks = 0; ks < 4; ++ks) {
                int cb = ks * 4 + lq;
                int scb = (cb & 8) | ((cb ^ key) & 7);
                bf16x8 kf = *(const bf16x8*)(Ksc + key * 128 + scb * 8);
                s0 = MFMA16(kf, qf[0][ks], s0);
                s1 = MFMA16(kf, qf[1][ks], s1);
            }
#pragma unroll
            for (int ks = 0; ks < 2; ++ks) {
                int cb = ks * 4 + lq;
                int scb = (cb ^ key) & 7;
                bf16x8 kf = *(const bf16x8*)(Ksr + key * 64 + scb * 8);
                s0 = MFMA16(kf, qf[0][4 + ks], s0);
                s1 = MFMA16(kf, qf[1][4 + ks], s1);
            }
            sacc0[kg] = s0; sacc1[kg] = s1;
        }
        __builtin_amdgcn_s_setprio(0);

        // physical key of sacc[kg][i] = kb + (kg>>1)*32 + lq*8 + (kg&1)*4 + i
        const bool domask = (kb + 63) > qrow_w;
        if (domask) {
#pragma unroll
            for (int kg = 0; kg < 4; ++kg) {
                int keybase = kb + ((kg >> 1) << 5) + (lq << 3) + ((kg & 1) << 2);
#pragma unroll
                for (int i = 0; i < 4; ++i) {
                    if (keybase + i > qi0) sacc0[kg][i] = -3e38f;
                    if (keybase + i > qi1) sacc1[kg][i] = -3e38f;
                }
            }
        }

        // ---- row max per fragment: in-lane tree + 2 shfl ----
        float mx0, mx1;
        {
            f32x4 mv0, mv1;
#pragma unroll
            for (int i = 0; i < 4; ++i) {
                mv0[i] = fmaxf(fmaxf(sacc0[0][i], sacc0[1][i]), fmaxf(sacc0[2][i], sacc0[3][i]));
                mv1[i] = fmaxf(fmaxf(sacc1[0][i], sacc1[1][i]), fmaxf(sacc1[2][i], sacc1[3][i]));
            }
            mx0 = fmaxf(fmaxf(mv0[0], mv0[1]), fmaxf(mv0[2], mv0[3]));
            mx1 = fmaxf(fmaxf(mv1[0], mv1[1]), fmaxf(mv1[2], mv1[3]));
            mx0 = fmaxf(mx0, __shfl_xor(mx0, 16, 64));
            mx0 = fmaxf(mx0, __shfl_xor(mx0, 32, 64));
            mx1 = fmaxf(mx1, __shfl_xor(mx1, 16, 64));
            mx1 = fmaxf(mx1, __shfl_xor(mx1, 32, 64));
        }

        // ---- defer-max rescale ----
        if (__any((mx0 > mrow0) | (mx1 > mrow1))) {
            float mnew0 = fmaxf(mrow0, mx0);
            float mnew1 = fmaxf(mrow1, mx1);
            float scl0 = __builtin_amdgcn_exp2f(mrow0 - mnew0);
            float scl1 = __builtin_amdgcn_exp2f(mrow1 - mnew1);
            mrow0 = mnew0; mrow1 = mnew1;
            lsum0 *= scl0; lsum1 *= scl1;
#pragma unroll
            for (int n = 0; n < 8; ++n)
#pragma unroll
                for (int i = 0; i < 4; ++i) {
                    o[0][n][i] *= scl0;
                    o[1][n][i] *= scl1;
                }
        }

        // ---- P = exp2(S - m), in-lane sum + 2 shfl ----
        f32x4 sv0 = z, sv1 = z;
#pragma unroll
        for (int kg = 0; kg < 4; ++kg)
#pragma unroll
            for (int i = 0; i < 4; ++i) {
                float p0 = __builtin_amdgcn_exp2f(sacc0[kg][i] - mrow0);
                float p1 = __builtin_amdgcn_exp2f(sacc1[kg][i] - mrow1);
                sacc0[kg][i] = p0; sacc1[kg][i] = p1;
                sv0[i] += p0; sv1[i] += p1;
            }
        float rs0 = (sv0[0] + sv0[1]) + (sv0[2] + sv0[3]);
        float rs1 = (sv1[0] + sv1[1]) + (sv1[2] + sv1[3]);
        rs0 += __shfl_xor(rs0, 16, 64);
        rs0 += __shfl_xor(rs0, 32, 64);
        rs1 += __shfl_xor(rs1, 16, 64);
        rs1 += __shfl_xor(rs1, 32, 64);
        lsum0 += rs0; lsum1 += rs1;

        // ---- O^T += V^T P : each vfr read feeds BOTH fragments ----
        __builtin_amdgcn_s_setprio(1);
#pragma unroll
        for (int s = 0; s < 2; ++s) {
            union { int4 iv; bf16x8 v; } pb0, pb1;
            pb0.iv.x = pack_bf16(sacc0[2 * s][0], sacc0[2 * s][1]);
            pb0.iv.y = pack_bf16(sacc0[2 * s][2], sacc0[2 * s][3]);
            pb0.iv.z = pack_bf16(sacc0[2 * s + 1][0], sacc0[2 * s + 1][1]);
            pb0.iv.w = pack_bf16(sacc0[2 * s + 1][2], sacc0[2 * s + 1][3]);
            pb1.iv.x = pack_bf16(sacc1[2 * s][0], sacc1[2 * s][1]);
            pb1.iv.y = pack_bf16(sacc1[2 * s][2], sacc1[2 * s][3]);
            pb1.iv.z = pack_bf16(sacc1[2 * s + 1][0], sacc1[2 * s + 1][1]);
            pb1.iv.w = pack_bf16(sacc1[2 * s + 1][2], sacc1[2 * s + 1][3]);
#pragma unroll
            for (int n = 0; n < 8; ++n) {
                int feat = n * 16 + lr;
                int scb = ((s * 4 + lq) ^ (feat & 7)) & 7;
                bf16x8 vfr = *(const bf16x8*)(Vt + feat * 64 + scb * 8);
                o[0][n] = MFMA16(vfr, pb0.v, o[0][n]);
                o[1][n] = MFMA16(vfr, pb1.v, o[1][n]);
            }
        }
        __builtin_amdgcn_s_setprio(0);
    }

    // lane holds O^T[dv = n*16 + lq*4 + i][qrow] for both fragments
    const float inv0 = 1.f / lsum0;
    const float inv1 = 1.f / lsum1;
    const size_t orow0 = (rowbase + qi0) * 2048 + h * 128;
    const size_t orow1 = (rowbase + qi1) * 2048 + h * 128;
#pragma unroll
    for (int n = 0; n < 8; ++n) {
        bf16x4 ov0, ov1;
#pragma unroll
        for (int i = 0; i < 4; ++i) {
            ov0[i] = (bf16)(o[0][n][i] * inv0);
            ov1[i] = (bf16)(o[1][n][i] * inv1);
        }
        *(bf16x4*)(att + orow0 + n * 16 + (lq << 2)) = ov0;
        *(bf16x4*)(att + orow1 + n * 16 + (lq << 2)) = ov1;
    }
}

// ---------------- host launch ----------------
extern "C" void kernel_launch(void* const* d_in, const int* in_sizes, int n_in,
                              void* d_out, int out_size, void* d_ws, size_t ws_size,
                              hipStream_t stream)
{
    (void)in_sizes; (void)n_in; (void)out_size; (void)ws_size;
    const float* x = (const float*)d_in[0];
    const float* w_ckv = (const float*)d_in[1];
    const float* w_kv = (const float*)d_in[2];
    const float* w_cq = (const float*)d_in[3];
    const float* w_q = (const float*)d_in[4];
    const float* w_qr = (const float*)d_in[5];
    const float* w_kr = (const float*)d_in[6];
    const float* w_out = (const float*)d_in[7];
    float* out = (float*)d_out;

    char* ws = (char*)d_ws;
    size_t off = 0;
    auto take = [&](size_t elems) -> bf16* {
        bf16* p = (bf16*)(ws + off);
        off += (elems * sizeof(bf16) + 255) & ~(size_t)255;
        return p;
    };
    bf16* WCT    = take(1024ull * 2048);   // [ckv|cq]^T
    bf16* WKVKRT = take(4160ull * 512);    // [kv|kr]^T
    bf16* WQQRT  = take(3072ull * 512);    // [q|qr]^T
    bf16* C      = take(4096ull * 1024);   // [c_kv | c_q] packed, stride 1024
    bf16* KVKR   = take(4096ull * 4160);   // [k_c | v | k_r] packed, stride 4160
    bf16* QCR    = take(4096ull * 3072);   // [q_c | q_r] packed, stride 3072
    bf16* ATT    = take(4096ull * 2048);
    bf16* WOUTT  = C;     // 8 MB alias (C dead after the dual GEMM)
    bf16* XB     = KVKR;  // 16.8 MB alias (XB dead before KVKR is written)

    // weight transposes + x convert, one dispatch
    k_cvtAll<<<7712, 256, 0, stream>>>(w_ckv, w_kv, w_cq, w_q, w_qr, w_kr,
                                       WCT, WKVKRT, WQQRT, x, XB);

    // C = x @ [W_ckv | W_cq]   (M=4096, N=1024, K=2048; 128x64 tiles)
    k_gemm_bt<4, 2, false><<<dim3(16, 32), 256, 0, stream>>>(
        XB, WCT, C, nullptr, 4096, 1024, 2048, 2048, 1.0f);

    // KVKR = c_kv @ [W_kv | W_kr]  and  QCR = scale * (c_q @ [W_q | W_qr]),
    // fused; RoPE applied in the epilogue.
    k_gemm_dual<<<1824, 256, 0, stream>>>(C, WKVKRT, WQQRT, KVKR, QCR);

    k_cvtT<<<dim3(64, 64), 256, 0, stream>>>(w_out, WOUTT, 2048, 2048);  // C dead now

    k_attn<<<512, 256, 0, stream>>>(QCR, KVKR, ATT);

    // out = att @ W_out   (N=2048, K=2048, f32 out; 64x128 tiles -> 1024 blocks)
    k_gemm_bt<2, 4, true><<<dim3(16, 64), 256, 0, stream>>>(
        ATT, WOUTT, nullptr, out, 4096, 2048, 2048, 2048, 1.0f);
}

// Round 15
// 247.463 us; speedup vs baseline: 1.1075x; 1.1075x over previous
//
#include <hip/hip_runtime.h>
#include <hip/hip_bf16.h>
#include <cstdint>
#include <cstddef>

typedef __bf16 bf16;
typedef __attribute__((ext_vector_type(2))) __bf16 bf16x2;
typedef __attribute__((ext_vector_type(4))) __bf16 bf16x4;
typedef __attribute__((ext_vector_type(8))) __bf16 bf16x8;
typedef __attribute__((ext_vector_type(4))) float f32x4;

#define MFMA16(a, b, c) __builtin_amdgcn_mfma_f32_16x16x32_bf16((a), (b), (c), 0, 0, 0)
// softmax runs in exp2 domain; scale folded into QCR GEMM epilogue
#define SCALE_L2E 0.127517432f

//  QCR row: [0..2047]=q_c (h*128+d), [2048..3071]=q_r (h*64+r)    stride 3072
//  KVKR row: [0..2047]=k_c, [2048..4095]=v, [4096..4159]=k_r      stride 4160
#define QCR_STRIDE 3072
#define KV_STRIDE  4160

__device__ __forceinline__ void gload16(const void* g, void* l) {
    __builtin_amdgcn_global_load_lds(
        (const __attribute__((address_space(1))) void*)g,
        (__attribute__((address_space(3))) void*)l, 16, 0, 0);
}

// barrier WITHOUT vmcnt drain (register prefetch stays in flight)
__device__ __forceinline__ void bar_lgkm() {
    asm volatile("s_waitcnt lgkmcnt(0)" ::: "memory");
    __builtin_amdgcn_s_barrier();
    asm volatile("" ::: "memory");
}

__device__ __forceinline__ int pack_bf16(float a, float b) {
    bf16x2 p; p[0] = (bf16)a; p[1] = (bf16)b;
    return __builtin_bit_cast(int, p);
}

// ---------------- merged convert dispatch ----------------
__global__ __launch_bounds__(256) void k_cvtAll(
    const float* __restrict__ w_ckv, const float* __restrict__ w_kv,
    const float* __restrict__ w_cq, const float* __restrict__ w_q,
    const float* __restrict__ w_qr, const float* __restrict__ w_kr,
    bf16* __restrict__ WCT, bf16* __restrict__ WKVKRT, bf16* __restrict__ WQQRT,
    const float* __restrict__ x, bf16* __restrict__ XB)
{
    __shared__ float tile[32][33];
    int bid = blockIdx.x;
    const int t = threadIdx.x;
    if (bid >= 5664) {
        int n4 = (4096 * 2048) / 4;
        int i = (bid - 5664) * 256 + t;
        int stride = 2048 * 256;
        const float4* in4 = (const float4*)x;
        bf16x4* o4 = (bf16x4*)XB;
        for (; i < n4; i += stride) {
            float4 v = in4[i];
            bf16x4 o;
            o[0] = (bf16)v.x; o[1] = (bf16)v.y; o[2] = (bf16)v.z; o[3] = (bf16)v.w;
            o4[i] = o;
        }
        return;
    }
    const float* src; bf16* dst; int Kd, Nd, loc;
    if (bid < 1024)      { src = w_ckv; dst = WCT;                   Kd = 2048; Nd = 512;  loc = bid; }
    else if (bid < 3072) { src = w_kv;  dst = WKVKRT;                Kd = 512;  Nd = 4096; loc = bid - 1024; }
    else if (bid < 4096) { src = w_cq;  dst = WCT + 512ull * 2048;   Kd = 2048; Nd = 512;  loc = bid - 3072; }
    else if (bid < 5120) { src = w_q;   dst = WQQRT;                 Kd = 512;  Nd = 2048; loc = bid - 4096; }
    else if (bid < 5632) { src = w_qr;  dst = WQQRT + 2048ull * 512; Kd = 512;  Nd = 1024; loc = bid - 5120; }
    else                 { src = w_kr;  dst = WKVKRT + 4096ull * 512; Kd = 512; Nd = 64;   loc = bid - 5632; }
    const int nbx = Nd / 32;
    const int n0 = (loc % nbx) * 32, k0 = (loc / nbx) * 32;
    const int r = t >> 3, c4 = (t & 7) * 4;
    float4 v = *(const float4*)(src + (size_t)(k0 + r) * Nd + n0 + c4);
    tile[r][c4 + 0] = v.x; tile[r][c4 + 1] = v.y;
    tile[r][c4 + 2] = v.z; tile[r][c4 + 3] = v.w;
    __syncthreads();
    bf16x4 o;
    o[0] = (bf16)tile[c4 + 0][r]; o[1] = (bf16)tile[c4 + 1][r];
    o[2] = (bf16)tile[c4 + 2][r]; o[3] = (bf16)tile[c4 + 3][r];
    *(bf16x4*)(dst + (size_t)(n0 + r) * Kd + k0 + c4) = o;
}

// ---------------- f32 -> bf16 transpose-convert (single weight, w_out) ----------------
__global__ __launch_bounds__(256) void k_cvtT(const float* __restrict__ in,
                                              bf16* __restrict__ out, int Kd, int Nd)
{
    __shared__ float tile[32][33];
    const int k0 = blockIdx.y * 32, n0 = blockIdx.x * 32;
    const int t = threadIdx.x;
    const int r = t >> 3, c4 = (t & 7) * 4;
    float4 v = *(const float4*)(in + (size_t)(k0 + r) * Nd + n0 + c4);
    tile[r][c4 + 0] = v.x; tile[r][c4 + 1] = v.y;
    tile[r][c4 + 2] = v.z; tile[r][c4 + 3] = v.w;
    __syncthreads();
    bf16x4 o;
    o[0] = (bf16)tile[c4 + 0][r]; o[1] = (bf16)tile[c4 + 1][r];
    o[2] = (bf16)tile[c4 + 2][r]; o[3] = (bf16)tile[c4 + 3][r];
    *(bf16x4*)(out + (size_t)(n0 + r) * Kd + k0 + c4) = o;
}

// ---------------- shared GEMM body ----------------
template<int MF, int NF, bool F32OUT, bool ROPE>
__device__ __forceinline__ void gemm_body(
    const bf16* __restrict__ A, const bf16* __restrict__ BT,
    bf16* __restrict__ Cb, float* __restrict__ Cf,
    int M, int N, int K, int lda, float cscale, int ropeStart, int bx, int by,
    bf16* As, bf16* Bs)
{
    constexpr int ASTR = MF * 1024, BSTR = NF * 1024;
    const int t = threadIdx.x;
    const int m0 = by * (MF * 32);
    const int n0 = bx * (NF * 32);
    const int wid = t >> 6, lane = t & 63;
    const int wm = (wid >> 1) * (MF * 16), wn = (wid & 1) * (NF * 16);
    const int lr = lane & 15, lk = (lane >> 4) * 8;

    const int srow = t >> 2, skc = (t & 3) << 3;
    const int bn0 = min(n0 + srow, N - 1);
    const int bn1 = min(n0 + srow + 64, N - 1);

    f32x4 acc[MF][NF];
    const f32x4 z = {0.f, 0.f, 0.f, 0.f};
#pragma unroll
    for (int m = 0; m < MF; ++m)
#pragma unroll
        for (int n = 0; n < NF; ++n) acc[m][n] = z;

    auto stage = [&](int buf, int k0) {
        gload16(BT + (size_t)bn0 * K + k0 + skc, Bs + buf * BSTR + t * 8);
        if constexpr (NF == 4)
            gload16(BT + (size_t)bn1 * K + k0 + skc, Bs + buf * BSTR + (t + 256) * 8);
        gload16(A + (size_t)(m0 + srow) * lda + k0 + skc, As + buf * ASTR + t * 8);
        if constexpr (MF == 4)
            gload16(A + (size_t)(m0 + srow + 64) * lda + k0 + skc, As + buf * ASTR + (t + 256) * 8);
    };

    stage(0, 0);
    __syncthreads();

    for (int k0 = 0; k0 < K; k0 += 32) {
        const int cur = (k0 >> 5) & 1;
        if (k0 + 32 < K) stage(cur ^ 1, k0 + 32);

        bf16x8 af[MF], bfr[NF];
#pragma unroll
        for (int m = 0; m < MF; ++m)
            af[m] = *(const bf16x8*)(As + cur * ASTR + (wm + m * 16 + lr) * 32 + lk);
#pragma unroll
        for (int n = 0; n < NF; ++n)
            bfr[n] = *(const bf16x8*)(Bs + cur * BSTR + (wn + n * 16 + lr) * 32 + lk);
#pragma unroll
        for (int m = 0; m < MF; ++m)
#pragma unroll
            for (int n = 0; n < NF; ++n)
                acc[m][n] = MFMA16(af[m], bfr[n], acc[m][n]);

        __syncthreads();
    }

    const int lrow4 = (lane >> 4) * 4;
#pragma unroll
    for (int m = 0; m < MF; ++m)
#pragma unroll
        for (int n = 0; n < NF; ++n)
#pragma unroll
            for (int i = 0; i < 4; ++i) {
                int r = m0 + wm + m * 16 + lrow4 + i;
                int c = n0 + wn + n * 16 + lr;
                float val = acc[m][n][i] * cscale;
                if constexpr (ROPE) {
                    float part = __shfl_xor(val, 1, 64);
                    if (c >= ropeStart) {
                        int i2 = ((c - ropeStart) & 63) >> 1;
                        int s = r & 2047;
                        float ang = (float)s * __expf(-(float)i2 * 0.28782313662f);
                        float sn, cs;
                        __sincosf(ang, &sn, &cs);
                        val = (c & 1) ? (part * sn + val * cs)
                                      : (val * cs - part * sn);
                    }
                }
                if (r < M && c < N) {
                    if constexpr (F32OUT) Cf[(size_t)r * N + c] = val;
                    else Cb[(size_t)r * N + c] = (bf16)val;
                }
            }
}

template<int MF, int NF, bool F32OUT>
__global__ __launch_bounds__(256) void k_gemm_bt(
    const bf16* __restrict__ A, const bf16* __restrict__ BT,
    bf16* __restrict__ Cb, float* __restrict__ Cf,
    int M, int N, int K, int lda, float cscale)
{
    __shared__ bf16 As[2 * MF * 1024];
    __shared__ bf16 Bs[2 * NF * 1024];
    gemm_body<MF, NF, F32OUT, false>(A, BT, Cb, Cf, M, N, K, lda, cscale, 1 << 30,
                                     blockIdx.x, blockIdx.y, As, Bs);
}

// KVKR (1056 blocks) + QCR (768 blocks) fused, RoPE in epilogue.
__global__ __launch_bounds__(256) void k_gemm_dual(
    const bf16* __restrict__ C, const bf16* __restrict__ WKVKRT,
    const bf16* __restrict__ WQQRT, bf16* __restrict__ KVKR, bf16* __restrict__ QCR)
{
    __shared__ bf16 As[2 * 4096];
    __shared__ bf16 Bs[2 * 4096];
    int bid = blockIdx.x;
    if (bid < 1056) {
        gemm_body<4, 4, false, true>(C, WKVKRT, KVKR, nullptr, 4096, 4160, 512, 1024,
                                     1.0f, 4096, bid % 33, bid / 33, As, Bs);
    } else {
        bid -= 1056;
        gemm_body<4, 4, false, true>(C + 512, WQQRT, QCR, nullptr, 4096, 3072, 512, 1024,
                                     SCALE_L2E, 2048, bid % 24, bid / 24, As, Bs);
    }
}

// ---------------- causal MLA attention (swapped QK^T, in-register P, dbuf LDS) ----------------
// r10/r12 proven structure: 1024 blocks x 256 threads, 64-row q-tiles heavy-first,
// 4 waves x 16 rows, rho-permuted swizzled K, in-register P. NEW: double-buffered
// K/V LDS -> ONE barrier per tile (was 2) and WRITE moved after compute (counted
// vmcnt for next tile's regs lands under this tile's MFMAs — true T14).
// Hazards: compute(buf[cur])@kt vs WRITE(buf[cur])@kt-1 and WRITE(buf[cur^1])@kt
// vs reads@kt-1 are both separated by the end-of-tile barrier. LDS 80KB -> 2
// blocks/CU (= measured effective residency of the 40KB version).
__global__ __launch_bounds__(256, 3) void k_attn(
    const bf16* __restrict__ qcr, const bf16* __restrict__ kvkr,
    bf16* __restrict__ att)
{
    __shared__ bf16 Ksc[2][64 * 128];  // [buf][rho(key)][feat 0..127], swizzled
    __shared__ bf16 Ksr[2][64 * 64];   // [buf][rho(key)][feat 128..191], swizzled
    __shared__ bf16 Vt[2][128 * 64];   // [buf][feat][key], swizzled

    const int L = blockIdx.x;
    const int qt = 31 - (L >> 5);   // 64-row q-tile, heavy first (LPT + backfill)
    const int bh = L & 31;
    const int h = bh & 15, b = bh >> 4;

    const int t = threadIdx.x;
    const int wid = t >> 6, lane = t & 63;
    const int lr = lane & 15, lq = lane >> 4, lk = lq * 8;
    const size_t rowbase = (size_t)b * 2048;

    const f32x4 z = {0.f, 0.f, 0.f, 0.f};

    auto rho = [](int r) {
        return (((r >> 5) & 1) << 5) | (((r >> 2) & 1) << 4) | (((r >> 3) & 3) << 2) | (r & 3);
    };

    const int vk = (t & 31) * 2;
    const int vf = (t >> 5) * 8;

    bf16x8 rc[4], rr[2], rv[4];
    auto LOAD = [&](int kb) {
#pragma unroll
        for (int i = 0; i < 4; ++i) {
            int bb = t + 256 * i;
            int row = bb >> 4, gcb = bb & 15;
            rc[i] = *(const bf16x8*)(kvkr + (rowbase + kb + row) * KV_STRIDE + h * 128 + gcb * 8);
        }
#pragma unroll
        for (int i = 0; i < 2; ++i) {
            int bb = t + 256 * i;
            int row = bb >> 3, gcb = bb & 7;
            rr[i] = *(const bf16x8*)(kvkr + (rowbase + kb + row) * KV_STRIDE + 4096 + gcb * 8);
        }
#pragma unroll
        for (int i = 0; i < 2; ++i) {
            const bf16* vs = kvkr + (rowbase + kb + vk) * KV_STRIDE + 2048 + h * 128 + vf + 64 * i;
            rv[2 * i]     = *(const bf16x8*)vs;
            rv[2 * i + 1] = *(const bf16x8*)(vs + KV_STRIDE);
        }
    };
    auto WRITE = [&](int bf) {
#pragma unroll
        for (int i = 0; i < 4; ++i) {
            int bb = t + 256 * i;
            int row = rho(bb >> 4), gcb = bb & 15;
            int scb = (gcb & 8) | ((gcb ^ row) & 7);
            *(bf16x8*)(&Ksc[bf][row * 128 + scb * 8]) = rc[i];
        }
#pragma unroll
        for (int i = 0; i < 2; ++i) {
            int bb = t + 256 * i;
            int row = rho(bb >> 3), gcb = bb & 7;
            int scb = (gcb ^ row) & 7;
            *(bf16x8*)(&Ksr[bf][row * 64 + scb * 8]) = rr[i];
        }
#pragma unroll
        for (int i = 0; i < 2; ++i)
#pragma unroll
            for (int j = 0; j < 8; ++j) {
                int feat = vf + 64 * i + j;
                int scb = ((vk >> 3) ^ (feat & 7)) & 7;
                bf16x2 pr; pr[0] = rv[2 * i][j]; pr[1] = rv[2 * i + 1][j];
                *(bf16x2*)(&Vt[bf][feat * 64 + scb * 8 + (vk & 7)]) = pr;
            }
    };

    const int qrow_w = qt * 64 + wid * 16;
    const int qi = qrow_w + lr;

    bf16x8 qf[6];
    {
        const size_t qrow = rowbase + qi;
        const bf16* qp = qcr + qrow * QCR_STRIDE + h * 128;
#pragma unroll
        for (int ks = 0; ks < 4; ++ks) qf[ks] = *(const bf16x8*)(qp + ks * 32 + lk);
        const bf16* qp2 = qcr + qrow * QCR_STRIDE + 2048 + h * 64;
#pragma unroll
        for (int ks = 0; ks < 2; ++ks) qf[4 + ks] = *(const bf16x8*)(qp2 + ks * 32 + lk);
    }

    float mrow = -3e38f, lsum = 0.f;
    f32x4 o[8];
#pragma unroll
    for (int n = 0; n < 8; ++n) o[n] = z;

    const int nkt = qt + 1;
    // prologue: tile 0 -> buf0; tile 1 -> regs (stays in flight)
    LOAD(0);
    WRITE(0);
    if (nkt > 1) LOAD(64);
    bar_lgkm();

#pragma unroll 1
    for (int kt = 0; kt < nkt; ++kt) {
        const int kb = kt * 64;
        const int cur = kt & 1;

        if (kb <= qrow_w + 15) {
            // ---- S^T = K Q^T (buffer cur) ----
            f32x4 sacc[4];
            __builtin_amdgcn_s_setprio(1);
#pragma unroll
            for (int kg = 0; kg < 4; ++kg) {
                f32x4 s = z;
                const int key = kg * 16 + lr;
#pragma unroll
                for (int ks = 0; ks < 4; ++ks) {
                    int cb = ks * 4 + lq;
                    int scb = (cb & 8) | ((cb ^ key) & 7);
                    bf16x8 kf = *(const bf16x8*)(&Ksc[cur][key * 128 + scb * 8]);
                    s = MFMA16(kf, qf[ks], s);
                }
#pragma unroll
                for (int ks = 0; ks < 2; ++ks) {
                    int cb = ks * 4 + lq;
                    int scb = (cb ^ key) & 7;
                    bf16x8 kf = *(const bf16x8*)(&Ksr[cur][key * 64 + scb * 8]);
                    s = MFMA16(kf, qf[4 + ks], s);
                }
                sacc[kg] = s;
            }
            __builtin_amdgcn_s_setprio(0);

            // physical key of sacc[kg][i] = kb + (kg>>1)*32 + lq*8 + (kg&1)*4 + i
            const bool domask = (kb + 63) > qrow_w;
            if (domask) {
#pragma unroll
                for (int kg = 0; kg < 4; ++kg) {
                    int keybase = kb + ((kg >> 1) << 5) + (lq << 3) + ((kg & 1) << 2);
#pragma unroll
                    for (int i = 0; i < 4; ++i)
                        if (keybase + i > qi) sacc[kg][i] = -3e38f;
                }
            }

            // ---- row max: in-lane tree + 2 shfl ----
            f32x4 mv;
#pragma unroll
            for (int i = 0; i < 4; ++i)
                mv[i] = fmaxf(fmaxf(sacc[0][i], sacc[1][i]), fmaxf(sacc[2][i], sacc[3][i]));
            float mx = fmaxf(fmaxf(mv[0], mv[1]), fmaxf(mv[2], mv[3]));
            mx = fmaxf(mx, __shfl_xor(mx, 16, 64));
            mx = fmaxf(mx, __shfl_xor(mx, 32, 64));

            // ---- defer-max rescale ----
            if (__any(mx > mrow)) {
                float mnew = fmaxf(mrow, mx);
                float scl = __builtin_amdgcn_exp2f(mrow - mnew);
                mrow = mnew;
                lsum *= scl;
#pragma unroll
                for (int n = 0; n < 8; ++n)
#pragma unroll
                    for (int i = 0; i < 4; ++i) o[n][i] *= scl;
            }

            // ---- P = exp2(S - m), in-lane sum + 2 shfl ----
            f32x4 sv = z;
#pragma unroll
            for (int kg = 0; kg < 4; ++kg)
#pragma unroll
                for (int i = 0; i < 4; ++i) {
                    float pv = __builtin_amdgcn_exp2f(sacc[kg][i] - mrow);
                    sacc[kg][i] = pv;
                    sv[i] += pv;
                }
            float rs = (sv[0] + sv[1]) + (sv[2] + sv[3]);
            rs += __shfl_xor(rs, 16, 64);
            rs += __shfl_xor(rs, 32, 64);
            lsum += rs;

            // ---- O^T += V^T P (buffer cur) ----
            __builtin_amdgcn_s_setprio(1);
#pragma unroll
            for (int s = 0; s < 2; ++s) {
                union { int4 iv; bf16x8 v; } pb;
                pb.iv.x = pack_bf16(sacc[2 * s][0], sacc[2 * s][1]);
                pb.iv.y = pack_bf16(sacc[2 * s][2], sacc[2 * s][3]);
                pb.iv.z = pack_bf16(sacc[2 * s + 1][0], sacc[2 * s + 1][1]);
                pb.iv.w = pack_bf16(sacc[2 * s + 1][2], sacc[2 * s + 1][3]);
#pragma unroll
                for (int n = 0; n < 8; ++n) {
                    int feat = n * 16 + lr;
                    int scb = ((s * 4 + lq) ^ (feat & 7)) & 7;
                    bf16x8 vfr = *(const bf16x8*)(&Vt[cur][feat * 64 + scb * 8]);
                    o[n] = MFMA16(vfr, pb.v, o[n]);
                }
            }
            __builtin_amdgcn_s_setprio(0);
        }

        // write-late staging: tile kt+1 regs -> buf[cur^1] (counted vmcnt lands
        // here, hidden under the compute above); then issue tile kt+2 loads.
        if (kt + 1 < nkt) {
            WRITE(cur ^ 1);
            if (kt + 2 < nkt) LOAD(kb + 128);
        }
        bar_lgkm();   // single end-of-tile barrier
    }

    // lane holds O^T[dv = n*16 + lq*4 + i][qrow = qi]
    const float inv = 1.f / lsum;
    const size_t orow = (rowbase + qi) * 2048 + h * 128;
#pragma unroll
    for (int n = 0; n < 8; ++n) {
        bf16x4 ov;
#pragma unroll
        for (int i = 0; i < 4; ++i) ov[i] = (bf16)(o[n][i] * inv);
        *(bf16x4*)(att + orow + n * 16 + (lq << 2)) = ov;
    }
}

// ---------------- host launch ----------------
extern "C" void kernel_launch(void* const* d_in, const int* in_sizes, int n_in,
                              void* d_out, int out_size, void* d_ws, size_t ws_size,
                              hipStream_t stream)
{
    (void)in_sizes; (void)n_in; (void)out_size; (void)ws_size;
    const float* x = (const float*)d_in[0];
    const float* w_ckv = (const float*)d_in[1];
    const float* w_kv = (const float*)d_in[2];
    const float* w_cq = (const float*)d_in[3];
    const float* w_q = (const float*)d_in[4];
    const float* w_qr = (const float*)d_in[5];
    const float* w_kr = (const float*)d_in[6];
    const float* w_out = (const float*)d_in[7];
    float* out = (float*)d_out;

    char* ws = (char*)d_ws;
    size_t off = 0;
    auto take = [&](size_t elems) -> bf16* {
        bf16* p = (bf16*)(ws + off);
        off += (elems * sizeof(bf16) + 255) & ~(size_t)255;
        return p;
    };
    bf16* WCT    = take(1024ull * 2048);   // [ckv|cq]^T
    bf16* WKVKRT = take(4160ull * 512);    // [kv|kr]^T
    bf16* WQQRT  = take(3072ull * 512);    // [q|qr]^T
    bf16* C      = take(4096ull * 1024);   // [c_kv | c_q] packed, stride 1024
    bf16* KVKR   = take(4096ull * 4160);   // [k_c | v | k_r] packed, stride 4160
    bf16* QCR    = take(4096ull * 3072);   // [q_c | q_r] packed, stride 3072
    bf16* ATT    = take(4096ull * 2048);
    bf16* WOUTT  = C;     // 8 MB alias (C dead after the dual GEMM)
    bf16* XB     = KVKR;  // 16.8 MB alias (XB dead before KVKR is written)

    // weight transposes + x convert, one dispatch
    k_cvtAll<<<7712, 256, 0, stream>>>(w_ckv, w_kv, w_cq, w_q, w_qr, w_kr,
                                       WCT, WKVKRT, WQQRT, x, XB);

    // C = x @ [W_ckv | W_cq]   (M=4096, N=1024, K=2048; 128x64 tiles)
    k_gemm_bt<4, 2, false><<<dim3(16, 32), 256, 0, stream>>>(
        XB, WCT, C, nullptr, 4096, 1024, 2048, 2048, 1.0f);

    // KVKR = c_kv @ [W_kv | W_kr]  and  QCR = scale * (c_q @ [W_q | W_qr]),
    // fused; RoPE applied in the epilogue.
    k_gemm_dual<<<1824, 256, 0, stream>>>(C, WKVKRT, WQQRT, KVKR, QCR);

    k_cvtT<<<dim3(64, 64), 256, 0, stream>>>(w_out, WOUTT, 2048, 2048);  // C dead now

    k_attn<<<1024, 256, 0, stream>>>(QCR, KVKR, ATT);

    // out = att @ W_out   (N=2048, K=2048, f32 out; 64x128 tiles -> 1024 blocks)
    k_gemm_bt<2, 4, true><<<dim3(16, 64), 256, 0, stream>>>(
        ATT, WOUTT, nullptr, out, 4096, 2048, 2048, 2048, 1.0f);
}

// Round 16
// 247.091 us; speedup vs baseline: 1.1092x; 1.0015x over previous
//
#include <hip/hip_runtime.h>
#include <hip/hip_bf16.h>
#include <cstdint>
#include <cstddef>

typedef __bf16 bf16;
typedef __attribute__((ext_vector_type(2))) __bf16 bf16x2;
typedef __attribute__((ext_vector_type(4))) __bf16 bf16x4;
typedef __attribute__((ext_vector_type(8))) __bf16 bf16x8;
typedef __attribute__((ext_vector_type(4))) float f32x4;

#define MFMA16(a, b, c) __builtin_amdgcn_mfma_f32_16x16x32_bf16((a), (b), (c), 0, 0, 0)
// softmax runs in exp2 domain; scale folded into QCR GEMM epilogue
#define SCALE_L2E 0.127517432f

//  QCR row: [0..2047]=q_c (h*128+d), [2048..3071]=q_r (h*64+r)    stride 3072
//  KVKR row: [0..2047]=k_c, [2048..4095]=v, [4096..4159]=k_r      stride 4160
#define QCR_STRIDE 3072
#define KV_STRIDE  4160

__device__ __forceinline__ void gload16(const void* g, void* l) {
    __builtin_amdgcn_global_load_lds(
        (const __attribute__((address_space(1))) void*)g,
        (__attribute__((address_space(3))) void*)l, 16, 0, 0);
}

// barrier WITHOUT vmcnt drain (register prefetch stays in flight)
__device__ __forceinline__ void bar_lgkm() {
    asm volatile("s_waitcnt lgkmcnt(0)" ::: "memory");
    __builtin_amdgcn_s_barrier();
    asm volatile("" ::: "memory");
}

__device__ __forceinline__ int pack_bf16(float a, float b) {
    bf16x2 p; p[0] = (bf16)a; p[1] = (bf16)b;
    return __builtin_bit_cast(int, p);
}

// ---------------- merged convert dispatch ----------------
__global__ __launch_bounds__(256) void k_cvtAll(
    const float* __restrict__ w_ckv, const float* __restrict__ w_kv,
    const float* __restrict__ w_cq, const float* __restrict__ w_q,
    const float* __restrict__ w_qr, const float* __restrict__ w_kr,
    bf16* __restrict__ WCT, bf16* __restrict__ WKVKRT, bf16* __restrict__ WQQRT,
    const float* __restrict__ x, bf16* __restrict__ XB)
{
    __shared__ float tile[32][33];
    int bid = blockIdx.x;
    const int t = threadIdx.x;
    if (bid >= 5664) {
        int n4 = (4096 * 2048) / 4;
        int i = (bid - 5664) * 256 + t;
        int stride = 2048 * 256;
        const float4* in4 = (const float4*)x;
        bf16x4* o4 = (bf16x4*)XB;
        for (; i < n4; i += stride) {
            float4 v = in4[i];
            bf16x4 o;
            o[0] = (bf16)v.x; o[1] = (bf16)v.y; o[2] = (bf16)v.z; o[3] = (bf16)v.w;
            o4[i] = o;
        }
        return;
    }
    const float* src; bf16* dst; int Kd, Nd, loc;
    if (bid < 1024)      { src = w_ckv; dst = WCT;                   Kd = 2048; Nd = 512;  loc = bid; }
    else if (bid < 3072) { src = w_kv;  dst = WKVKRT;                Kd = 512;  Nd = 4096; loc = bid - 1024; }
    else if (bid < 4096) { src = w_cq;  dst = WCT + 512ull * 2048;   Kd = 2048; Nd = 512;  loc = bid - 3072; }
    else if (bid < 5120) { src = w_q;   dst = WQQRT;                 Kd = 512;  Nd = 2048; loc = bid - 4096; }
    else if (bid < 5632) { src = w_qr;  dst = WQQRT + 2048ull * 512; Kd = 512;  Nd = 1024; loc = bid - 5120; }
    else                 { src = w_kr;  dst = WKVKRT + 4096ull * 512; Kd = 512; Nd = 64;   loc = bid - 5632; }
    const int nbx = Nd / 32;
    const int n0 = (loc % nbx) * 32, k0 = (loc / nbx) * 32;
    const int r = t >> 3, c4 = (t & 7) * 4;
    float4 v = *(const float4*)(src + (size_t)(k0 + r) * Nd + n0 + c4);
    tile[r][c4 + 0] = v.x; tile[r][c4 + 1] = v.y;
    tile[r][c4 + 2] = v.z; tile[r][c4 + 3] = v.w;
    __syncthreads();
    bf16x4 o;
    o[0] = (bf16)tile[c4 + 0][r]; o[1] = (bf16)tile[c4 + 1][r];
    o[2] = (bf16)tile[c4 + 2][r]; o[3] = (bf16)tile[c4 + 3][r];
    *(bf16x4*)(dst + (size_t)(n0 + r) * Kd + k0 + c4) = o;
}

// ---------------- f32 -> bf16 transpose-convert (single weight, w_out) ----------------
__global__ __launch_bounds__(256) void k_cvtT(const float* __restrict__ in,
                                              bf16* __restrict__ out, int Kd, int Nd)
{
    __shared__ float tile[32][33];
    const int k0 = blockIdx.y * 32, n0 = blockIdx.x * 32;
    const int t = threadIdx.x;
    const int r = t >> 3, c4 = (t & 7) * 4;
    float4 v = *(const float4*)(in + (size_t)(k0 + r) * Nd + n0 + c4);
    tile[r][c4 + 0] = v.x; tile[r][c4 + 1] = v.y;
    tile[r][c4 + 2] = v.z; tile[r][c4 + 3] = v.w;
    __syncthreads();
    bf16x4 o;
    o[0] = (bf16)tile[c4 + 0][r]; o[1] = (bf16)tile[c4 + 1][r];
    o[2] = (bf16)tile[c4 + 2][r]; o[3] = (bf16)tile[c4 + 3][r];
    *(bf16x4*)(out + (size_t)(n0 + r) * Kd + k0 + c4) = o;
}

// ---------------- shared GEMM body ----------------
template<int MF, int NF, bool F32OUT, bool ROPE>
__device__ __forceinline__ void gemm_body(
    const bf16* __restrict__ A, const bf16* __restrict__ BT,
    bf16* __restrict__ Cb, float* __restrict__ Cf,
    int M, int N, int K, int lda, float cscale, int ropeStart, int bx, int by,
    bf16* As, bf16* Bs)
{
    constexpr int ASTR = MF * 1024, BSTR = NF * 1024;
    const int t = threadIdx.x;
    const int m0 = by * (MF * 32);
    const int n0 = bx * (NF * 32);
    const int wid = t >> 6, lane = t & 63;
    const int wm = (wid >> 1) * (MF * 16), wn = (wid & 1) * (NF * 16);
    const int lr = lane & 15, lk = (lane >> 4) * 8;

    const int srow = t >> 2, skc = (t & 3) << 3;
    const int bn0 = min(n0 + srow, N - 1);
    const int bn1 = min(n0 + srow + 64, N - 1);

    f32x4 acc[MF][NF];
    const f32x4 z = {0.f, 0.f, 0.f, 0.f};
#pragma unroll
    for (int m = 0; m < MF; ++m)
#pragma unroll
        for (int n = 0; n < NF; ++n) acc[m][n] = z;

    auto stage = [&](int buf, int k0) {
        gload16(BT + (size_t)bn0 * K + k0 + skc, Bs + buf * BSTR + t * 8);
        if constexpr (NF == 4)
            gload16(BT + (size_t)bn1 * K + k0 + skc, Bs + buf * BSTR + (t + 256) * 8);
        gload16(A + (size_t)(m0 + srow) * lda + k0 + skc, As + buf * ASTR + t * 8);
        if constexpr (MF == 4)
            gload16(A + (size_t)(m0 + srow + 64) * lda + k0 + skc, As + buf * ASTR + (t + 256) * 8);
    };

    stage(0, 0);
    __syncthreads();

    for (int k0 = 0; k0 < K; k0 += 32) {
        const int cur = (k0 >> 5) & 1;
        if (k0 + 32 < K) stage(cur ^ 1, k0 + 32);

        bf16x8 af[MF], bfr[NF];
#pragma unroll
        for (int m = 0; m < MF; ++m)
            af[m] = *(const bf16x8*)(As + cur * ASTR + (wm + m * 16 + lr) * 32 + lk);
#pragma unroll
        for (int n = 0; n < NF; ++n)
            bfr[n] = *(const bf16x8*)(Bs + cur * BSTR + (wn + n * 16 + lr) * 32 + lk);
#pragma unroll
        for (int m = 0; m < MF; ++m)
#pragma unroll
            for (int n = 0; n < NF; ++n)
                acc[m][n] = MFMA16(af[m], bfr[n], acc[m][n]);

        __syncthreads();
    }

    const int lrow4 = (lane >> 4) * 4;
#pragma unroll
    for (int m = 0; m < MF; ++m)
#pragma unroll
        for (int n = 0; n < NF; ++n)
#pragma unroll
            for (int i = 0; i < 4; ++i) {
                int r = m0 + wm + m * 16 + lrow4 + i;
                int c = n0 + wn + n * 16 + lr;
                float val = acc[m][n][i] * cscale;
                if constexpr (ROPE) {
                    float part = __shfl_xor(val, 1, 64);
                    if (c >= ropeStart) {
                        int i2 = ((c - ropeStart) & 63) >> 1;
                        int s = r & 2047;
                        float ang = (float)s * __expf(-(float)i2 * 0.28782313662f);
                        float sn, cs;
                        __sincosf(ang, &sn, &cs);
                        val = (c & 1) ? (part * sn + val * cs)
                                      : (val * cs - part * sn);
                    }
                }
                if (r < M && c < N) {
                    if constexpr (F32OUT) Cf[(size_t)r * N + c] = val;
                    else Cb[(size_t)r * N + c] = (bf16)val;
                }
            }
}

template<int MF, int NF, bool F32OUT>
__global__ __launch_bounds__(256) void k_gemm_bt(
    const bf16* __restrict__ A, const bf16* __restrict__ BT,
    bf16* __restrict__ Cb, float* __restrict__ Cf,
    int M, int N, int K, int lda, float cscale)
{
    __shared__ bf16 As[2 * MF * 1024];
    __shared__ bf16 Bs[2 * NF * 1024];
    gemm_body<MF, NF, F32OUT, false>(A, BT, Cb, Cf, M, N, K, lda, cscale, 1 << 30,
                                     blockIdx.x, blockIdx.y, As, Bs);
}

// KVKR (1056 blocks) + QCR (768 blocks) fused, RoPE in epilogue.
__global__ __launch_bounds__(256) void k_gemm_dual(
    const bf16* __restrict__ C, const bf16* __restrict__ WKVKRT,
    const bf16* __restrict__ WQQRT, bf16* __restrict__ KVKR, bf16* __restrict__ QCR)
{
    __shared__ bf16 As[2 * 4096];
    __shared__ bf16 Bs[2 * 4096];
    int bid = blockIdx.x;
    if (bid < 1056) {
        gemm_body<4, 4, false, true>(C, WKVKRT, KVKR, nullptr, 4096, 4160, 512, 1024,
                                     1.0f, 4096, bid % 33, bid / 33, As, Bs);
    } else {
        bid -= 1056;
        gemm_body<4, 4, false, true>(C + 512, WQQRT, QCR, nullptr, 4096, 3072, 512, 1024,
                                     SCALE_L2E, 2048, bid % 24, bid / 24, As, Bs);
    }
}

// ---------------- causal MLA attention (swapped QK^T, in-register P) ----------------
// r12-exact structure (best stable: 95.6us): 1024 blocks x 256 threads, 64-row
// q-tiles heavy-first, single-buffered K/V LDS (40KB), rho-permuted swizzled K,
// in-register P, setprio on MFMA clusters. NEW vs r12: T13 defer-max THRESHOLD=8
// (skip the 33-op o-rescale unless max grew >8; P bounded by 2^8, ratio exact).
__global__ __launch_bounds__(256, 3) void k_attn(
    const bf16* __restrict__ qcr, const bf16* __restrict__ kvkr,
    bf16* __restrict__ att)
{
    __shared__ bf16 Ksc[64 * 128];  // [rho(key)][feat 0..127], 16B-block swizzled
    __shared__ bf16 Ksr[64 * 64];   // [rho(key)][feat 128..191], swizzled
    __shared__ bf16 Vt[128 * 64];   // [feat][key], 16B-block swizzled

    const int L = blockIdx.x;
    const int qt = 31 - (L >> 5);   // 64-row q-tile, heavy first
    const int bh = L & 31;
    const int h = bh & 15, b = bh >> 4;

    const int t = threadIdx.x;
    const int wid = t >> 6, lane = t & 63;
    const int lr = lane & 15, lq = lane >> 4, lk = lq * 8;
    const size_t rowbase = (size_t)b * 2048;

    const f32x4 z = {0.f, 0.f, 0.f, 0.f};

    auto rho = [](int r) {
        return (((r >> 5) & 1) << 5) | (((r >> 2) & 1) << 4) | (((r >> 3) & 3) << 2) | (r & 3);
    };

    const int vk = (t & 31) * 2;
    const int vf = (t >> 5) * 8;

    bf16x8 rc[4], rr[2], rv[4];
    auto LOAD = [&](int kb) {
#pragma unroll
        for (int i = 0; i < 4; ++i) {
            int bb = t + 256 * i;
            int row = bb >> 4, gcb = bb & 15;
            rc[i] = *(const bf16x8*)(kvkr + (rowbase + kb + row) * KV_STRIDE + h * 128 + gcb * 8);
        }
#pragma unroll
        for (int i = 0; i < 2; ++i) {
            int bb = t + 256 * i;
            int row = bb >> 3, gcb = bb & 7;
            rr[i] = *(const bf16x8*)(kvkr + (rowbase + kb + row) * KV_STRIDE + 4096 + gcb * 8);
        }
#pragma unroll
        for (int i = 0; i < 2; ++i) {
            const bf16* vs = kvkr + (rowbase + kb + vk) * KV_STRIDE + 2048 + h * 128 + vf + 64 * i;
            rv[2 * i]     = *(const bf16x8*)vs;
            rv[2 * i + 1] = *(const bf16x8*)(vs + KV_STRIDE);
        }
    };
    auto WRITE = [&]() {
#pragma unroll
        for (int i = 0; i < 4; ++i) {
            int bb = t + 256 * i;
            int row = rho(bb >> 4), gcb = bb & 15;
            int scb = (gcb & 8) | ((gcb ^ row) & 7);
            *(bf16x8*)(Ksc + row * 128 + scb * 8) = rc[i];
        }
#pragma unroll
        for (int i = 0; i < 2; ++i) {
            int bb = t + 256 * i;
            int row = rho(bb >> 3), gcb = bb & 7;
            int scb = (gcb ^ row) & 7;
            *(bf16x8*)(Ksr + row * 64 + scb * 8) = rr[i];
        }
#pragma unroll
        for (int i = 0; i < 2; ++i)
#pragma unroll
            for (int j = 0; j < 8; ++j) {
                int feat = vf + 64 * i + j;
                int scb = ((vk >> 3) ^ (feat & 7)) & 7;
                bf16x2 pr; pr[0] = rv[2 * i][j]; pr[1] = rv[2 * i + 1][j];
                *(bf16x2*)(Vt + feat * 64 + scb * 8 + (vk & 7)) = pr;
            }
    };

    const int qrow_w = qt * 64 + wid * 16;
    const int qi = qrow_w + lr;

    bf16x8 qf[6];
    {
        const size_t qrow = rowbase + qi;
        const bf16* qp = qcr + qrow * QCR_STRIDE + h * 128;
#pragma unroll
        for (int ks = 0; ks < 4; ++ks) qf[ks] = *(const bf16x8*)(qp + ks * 32 + lk);
        const bf16* qp2 = qcr + qrow * QCR_STRIDE + 2048 + h * 64;
#pragma unroll
        for (int ks = 0; ks < 2; ++ks) qf[4 + ks] = *(const bf16x8*)(qp2 + ks * 32 + lk);
    }

    float mrow = -3e38f, lsum = 0.f;
    f32x4 o[8];
#pragma unroll
    for (int n = 0; n < 8; ++n) o[n] = z;

    const int nkt = qt + 1;
    LOAD(0);

#pragma unroll 1
    for (int kt = 0; kt < nkt; ++kt) {
        const int kb = kt * 64;
        bar_lgkm();
        WRITE();
        if (kt + 1 < nkt) LOAD(kb + 64);
        bar_lgkm();

        if (kb > qrow_w + 15) continue;

        // ---- S^T = K Q^T ----
        f32x4 sacc[4];
        __builtin_amdgcn_s_setprio(1);
#pragma unroll
        for (int kg = 0; kg < 4; ++kg) {
            f32x4 s = z;
            const int key = kg * 16 + lr;
#pragma unroll
            for (int ks = 0; ks < 4; ++ks) {
                int cb = ks * 4 + lq;
                int scb = (cb & 8) | ((cb ^ key) & 7);
                bf16x8 kf = *(const bf16x8*)(Ksc + key * 128 + scb * 8);
                s = MFMA16(kf, qf[ks], s);
            }
#pragma unroll
            for (int ks = 0; ks < 2; ++ks) {
                int cb = ks * 4 + lq;
                int scb = (cb ^ key) & 7;
                bf16x8 kf = *(const bf16x8*)(Ksr + key * 64 + scb * 8);
                s = MFMA16(kf, qf[4 + ks], s);
            }
            sacc[kg] = s;
        }
        __builtin_amdgcn_s_setprio(0);

        // physical key of sacc[kg][i] = kb + (kg>>1)*32 + lq*8 + (kg&1)*4 + i
        const bool domask = (kb + 63) > qrow_w;
        if (domask) {
#pragma unroll
            for (int kg = 0; kg < 4; ++kg) {
                int keybase = kb + ((kg >> 1) << 5) + (lq << 3) + ((kg & 1) << 2);
#pragma unroll
                for (int i = 0; i < 4; ++i)
                    if (keybase + i > qi) sacc[kg][i] = -3e38f;
            }
        }

        // ---- row max: in-lane tree + 2 shfl ----
        f32x4 mv;
#pragma unroll
        for (int i = 0; i < 4; ++i)
            mv[i] = fmaxf(fmaxf(sacc[0][i], sacc[1][i]), fmaxf(sacc[2][i], sacc[3][i]));
        float mx = fmaxf(fmaxf(mv[0], mv[1]), fmaxf(mv[2], mv[3]));
        mx = fmaxf(mx, __shfl_xor(mx, 16, 64));
        mx = fmaxf(mx, __shfl_xor(mx, 32, 64));

        // ---- T13 defer-max: rescale only if some lane's max grew by >8 ----
        // (P then bounded by 2^8; O = sum(P V)/sum(P) is scale-invariant.)
        if (__any(mx > mrow + 8.f)) {
            float mnew = fmaxf(mrow, mx);
            float scl = __builtin_amdgcn_exp2f(mrow - mnew);
            mrow = mnew;
            lsum *= scl;
#pragma unroll
            for (int n = 0; n < 8; ++n)
#pragma unroll
                for (int i = 0; i < 4; ++i) o[n][i] *= scl;
        }

        // ---- P = exp2(S - m), in-lane sum + 2 shfl ----
        f32x4 sv = z;
#pragma unroll
        for (int kg = 0; kg < 4; ++kg)
#pragma unroll
            for (int i = 0; i < 4; ++i) {
                float pv = __builtin_amdgcn_exp2f(sacc[kg][i] - mrow);
                sacc[kg][i] = pv;
                sv[i] += pv;
            }
        float rs = (sv[0] + sv[1]) + (sv[2] + sv[3]);
        rs += __shfl_xor(rs, 16, 64);
        rs += __shfl_xor(rs, 32, 64);
        lsum += rs;

        // ---- O^T += V^T P ----
        __builtin_amdgcn_s_setprio(1);
#pragma unroll
        for (int s = 0; s < 2; ++s) {
            union { int4 iv; bf16x8 v; } pb;
            pb.iv.x = pack_bf16(sacc[2 * s][0], sacc[2 * s][1]);
            pb.iv.y = pack_bf16(sacc[2 * s][2], sacc[2 * s][3]);
            pb.iv.z = pack_bf16(sacc[2 * s + 1][0], sacc[2 * s + 1][1]);
            pb.iv.w = pack_bf16(sacc[2 * s + 1][2], sacc[2 * s + 1][3]);
#pragma unroll
            for (int n = 0; n < 8; ++n) {
                int feat = n * 16 + lr;
                int scb = ((s * 4 + lq) ^ (feat & 7)) & 7;
                bf16x8 vfr = *(const bf16x8*)(Vt + feat * 64 + scb * 8);
                o[n] = MFMA16(vfr, pb.v, o[n]);
            }
        }
        __builtin_amdgcn_s_setprio(0);
    }

    const float inv = 1.f / lsum;
    const size_t orow = (rowbase + qi) * 2048 + h * 128;
#pragma unroll
    for (int n = 0; n < 8; ++n) {
        bf16x4 ov;
#pragma unroll
        for (int i = 0; i < 4; ++i) ov[i] = (bf16)(o[n][i] * inv);
        *(bf16x4*)(att + orow + n * 16 + (lq << 2)) = ov;
    }
}

// ---------------- host launch ----------------
extern "C" void kernel_launch(void* const* d_in, const int* in_sizes, int n_in,
                              void* d_out, int out_size, void* d_ws, size_t ws_size,
                              hipStream_t stream)
{
    (void)in_sizes; (void)n_in; (void)out_size; (void)ws_size;
    const float* x = (const float*)d_in[0];
    const float* w_ckv = (const float*)d_in[1];
    const float* w_kv = (const float*)d_in[2];
    const float* w_cq = (const float*)d_in[3];
    const float* w_q = (const float*)d_in[4];
    const float* w_qr = (const float*)d_in[5];
    const float* w_kr = (const float*)d_in[6];
    const float* w_out = (const float*)d_in[7];
    float* out = (float*)d_out;

    char* ws = (char*)d_ws;
    size_t off = 0;
    auto take = [&](size_t elems) -> bf16* {
        bf16* p = (bf16*)(ws + off);
        off += (elems * sizeof(bf16) + 255) & ~(size_t)255;
        return p;
    };
    bf16* WCT    = take(1024ull * 2048);   // [ckv|cq]^T
    bf16* WKVKRT = take(4160ull * 512);    // [kv|kr]^T
    bf16* WQQRT  = take(3072ull * 512);    // [q|qr]^T
    bf16* C      = take(4096ull * 1024);   // [c_kv | c_q] packed, stride 1024
    bf16* KVKR   = take(4096ull * 4160);   // [k_c | v | k_r] packed, stride 4160
    bf16* QCR    = take(4096ull * 3072);   // [q_c | q_r] packed, stride 3072
    bf16* ATT    = take(4096ull * 2048);
    bf16* WOUTT  = C;     // 8 MB alias (C dead after the dual GEMM)
    bf16* XB     = KVKR;  // 16.8 MB alias (XB dead before KVKR is written)

    // weight transposes + x convert, one dispatch
    k_cvtAll<<<7712, 256, 0, stream>>>(w_ckv, w_kv, w_cq, w_q, w_qr, w_kr,
                                       WCT, WKVKRT, WQQRT, x, XB);

    // C = x @ [W_ckv | W_cq]   (M=4096, N=1024, K=2048; 128x64 tiles)
    k_gemm_bt<4, 2, false><<<dim3(16, 32), 256, 0, stream>>>(
        XB, WCT, C, nullptr, 4096, 1024, 2048, 2048, 1.0f);

    // KVKR = c_kv @ [W_kv | W_kr]  and  QCR = scale * (c_q @ [W_q | W_qr]),
    // fused; RoPE applied in the epilogue.
    k_gemm_dual<<<1824, 256, 0, stream>>>(C, WKVKRT, WQQRT, KVKR, QCR);

    k_cvtT<<<dim3(64, 64), 256, 0, stream>>>(w_out, WOUTT, 2048, 2048);  // C dead now

    k_attn<<<1024, 256, 0, stream>>>(QCR, KVKR, ATT);

    // out = att @ W_out   (N=2048, K=2048, f32 out; 128x128 tiles -> 512 blocks)
    k_gemm_bt<4, 4, true><<<dim3(16, 32), 256, 0, stream>>>(
        ATT, WOUTT, nullptr, out, 4096, 2048, 2048, 2048, 1.0f);
}